// Round 4
// baseline (272.456 us; speedup 1.0000x reference)
//
#include <hip/hip_runtime.h>
#include <hip/hip_bf16.h>

#define TOKENS 2048
#define HIDDEN 1024
#define NEXP   8
#define INTER  2816
#define N1     5632   // 2*INTER
#define ROWCAP 5120   // 4096 pairs + 8*128 padding worst case
#define SPLITK 2      // gemm2 K-slices

typedef __attribute__((ext_vector_type(8))) short short8;   // 8 bf16 = 4 VGPR (MFMA A/B frag)
typedef __attribute__((ext_vector_type(4))) float f32x4;    // MFMA C/D frag

typedef unsigned int __attribute__((address_space(1))) as1_uint;
typedef unsigned int __attribute__((address_space(3))) as3_uint;

__device__ __forceinline__ void gload16(const void* g, void* l) {
  // async global->LDS, 16B/lane, LDS dest = wave-uniform base + lane*16
  __builtin_amdgcn_global_load_lds((const as1_uint*)g, (as3_uint*)l, 16, 0, 0);
}

__device__ __forceinline__ unsigned short f2bf(float f) {  // RNE f32->bf16 (bit trick)
  unsigned u = __float_as_uint(f);
  u += 0x7fff + ((u >> 16) & 1);
  return (unsigned short)(u >> 16);
}
__device__ __forceinline__ float bf2f(unsigned short h) {
  return __uint_as_float(((unsigned)h) << 16);
}
__device__ __forceinline__ unsigned short bfs(float x) {   // compiler fuses pairs to v_cvt_pk_bf16_f32
  __hip_bfloat16 h = __float2bfloat16(x);
  return *reinterpret_cast<unsigned short*>(&h);
}
__device__ __forceinline__ uint4 pack4(float4 a, float4 b) {  // 8 f32 -> 8 bf16 (16B)
  union { unsigned short us[8]; uint4 v; } o;
  o.us[0] = bfs(a.x); o.us[1] = bfs(a.y); o.us[2] = bfs(a.z); o.us[3] = bfs(a.w);
  o.us[4] = bfs(b.x); o.us[5] = bfs(b.y); o.us[6] = bfs(b.z); o.us[7] = bfs(b.w);
  return o.v;
}

// ---------------- routing: softmax->top2->renorm == sigmoid(l0-l1) ----------------
__global__ void k_routing(const float* __restrict__ gate, int* __restrict__ ctrl,
                          int* __restrict__ tkid, float* __restrict__ tkw) {
  int t = blockIdx.x * blockDim.x + threadIdx.x;
  if (t >= TOKENS) return;
  float l[8];
#pragma unroll
  for (int i = 0; i < 8; i++) l[i] = gate[t * 8 + i];
  int i0 = 0; float m0 = l[0];
#pragma unroll
  for (int i = 1; i < 8; i++) if (l[i] > m0) { m0 = l[i]; i0 = i; }
  int i1 = -1; float m1 = -3.4e38f;
#pragma unroll
  for (int i = 0; i < 8; i++) if (i != i0 && l[i] > m1) { m1 = l[i]; i1 = i; }
  float e  = __expf(m1 - m0);          // <= 1, stable
  float w0 = 1.f / (1.f + e);
  float w1 = e / (1.f + e);
  tkid[2 * t] = i0; tkid[2 * t + 1] = i1;
  tkw[2 * t] = w0;  tkw[2 * t + 1] = w1;
  atomicAdd(&ctrl[i0], 1);
  atomicAdd(&ctrl[i1], 1);
}

// ctrl layout (ints): [0..7]=cnt  [8..15]=cursor  [16..23]=base (128-aligned prefix)
__global__ void k_base(int* ctrl) {
  if (threadIdx.x == 0) {
    int a = 0;
    for (int e = 0; e < 8; e++) { ctrl[16 + e] = a; a += ((ctrl[e] + 127) >> 7) << 7; }
  }
}

__global__ void k_fill(int* __restrict__ ctrl, const int* __restrict__ tkid,
                       int* __restrict__ rtok, int* __restrict__ trow) {
  int t = blockIdx.x * blockDim.x + threadIdx.x;
  if (t >= TOKENS) return;
#pragma unroll
  for (int k = 0; k < 2; k++) {
    int e = tkid[2 * t + k];
    int pos = atomicAdd(&ctrl[8 + e], 1);
    int row = ctrl[16 + e] + pos;
    rtok[row] = t;
    trow[2 * t + k] = row;
  }
}

// gather x rows (f32) -> bf16 A matrix ordered by expert segment; zero padded rows
__global__ void k_gather(const float* __restrict__ x, const int* __restrict__ ctrl,
                         const int* __restrict__ rtok, unsigned short* __restrict__ Abf) {
  int row = blockIdx.x;
  int e = -1, local = 0;
  for (int i = 0; i < 8; i++) {
    int b = ctrl[16 + i], p = ((ctrl[i] + 127) >> 7) << 7;
    if (row >= b && row < b + p) { e = i; local = row - b; break; }
  }
  if (e < 0) return;
  int tid = threadIdx.x;
  unsigned short* dst = Abf + (size_t)row * HIDDEN;
  if (local < ctrl[e]) {
    int t = rtok[row];
    float4 v = ((const float4*)(x + (size_t)t * HIDDEN))[tid];
    ushort4 o; o.x = f2bf(v.x); o.y = f2bf(v.y); o.z = f2bf(v.z); o.w = f2bf(v.w);
    ((ushort4*)dst)[tid] = o;
  } else {
    ushort4 z; z.x = 0; z.y = 0; z.z = 0; z.w = 0;
    ((ushort4*)dst)[tid] = z;
  }
}

// expert/tile lookup shared by all GEMMs
__device__ __forceinline__ int tile_lookup(const int* ctrl, int mt, int* ml) {
  int a0 = 0;
  for (int i = 0; i < 8; i++) {
    int pt = (ctrl[i] + 127) >> 7;
    if (mt < a0 + pt) { *ml = mt - a0; return i; }
    a0 += pt;
  }
  return -1;
}

// ============ GEMM1: h = A(bf16,gload_lds) * w1[e](f32 -> reg -> cvt -> bf16 LDS)^T ============
// LDS: A [128][64] bf16, B [128][64] bf16 (16KB each), XOR-swizzle (row&7)<<4 on 16B blocks.
// B conversion on the WRITE side keeps the MFMA phase identical to the proven bf16 kernel.
__global__ __launch_bounds__(256, 3) void k_gemm1(const float* __restrict__ w1,
    const unsigned short* __restrict__ Abf, unsigned short* __restrict__ act,
    const int* __restrict__ ctrl) {
  union __align__(16) LdsU {
    struct { unsigned char A[16384]; unsigned char B[16384]; } st;
    unsigned short hb[128 * 132];
  };
  __shared__ LdsU lds;
  int mt = blockIdx.y, ml;
  int e = tile_lookup(ctrl, mt, &ml);
  if (e < 0) return;
  int nt = blockIdx.x;                               // 0..43 : inter cols [nt*64, nt*64+64)
  int tid = threadIdx.x, lane = tid & 63, wid = tid >> 6, wr = wid >> 1, wc = wid & 1;
  int rbase = ctrl[16 + e] + ml * 128;
  const unsigned char* Ab = (const unsigned char*)(Abf + (size_t)rbase * HIDDEN);
  int swzA = ((lane & 7) ^ (lane >> 3)) << 4;
  int l3 = lane >> 3, l4 = lane >> 4;

  // B reg-staging geometry: thread -> (row rr in 64-half, col-quarter q of 16 f32)
  int q = tid & 3, rr = tid >> 2, r7 = rr & 7;
  const float* g0 = w1 + (size_t)e * N1 * HIDDEN + (size_t)(nt * 64 + rr) * HIDDEN + q * 16;
  const float* g1 = g0 + (size_t)INTER * HIDDEN;
  unsigned wo00 = rr * 128        + (((2 * q)     ^ r7) << 4);
  unsigned wo01 = rr * 128        + (((2 * q + 1) ^ r7) << 4);
  unsigned wo10 = (64 + rr) * 128 + (((2 * q)     ^ r7) << 4);
  unsigned wo11 = (64 + rr) * 128 + (((2 * q + 1) ^ r7) << 4);

  f32x4 acc[4][4];
  f32x4 zero = {0.f, 0.f, 0.f, 0.f};
#pragma unroll
  for (int i = 0; i < 4; i++)
#pragma unroll
    for (int j = 0; j < 4; j++) acc[i][j] = zero;

  for (int kk = 0; kk < HIDDEN / 64; ++kk) {
    // issue all B f32 loads first (ILP), then A async gloads, then cvt+write
    const float4* p0 = (const float4*)(g0 + kk * 64);
    const float4* p1 = (const float4*)(g1 + kk * 64);
    float4 b0 = p0[0], b1 = p0[1], b2 = p0[2], b3 = p0[3];
    float4 c0 = p1[0], c1 = p1[1], c2 = p1[2], c3 = p1[3];
#pragma unroll
    for (int i = 0; i < 4; i++) {
      int g = wid * 4 + i;                           // 16 groups of 8 A-rows
      gload16(Ab + (size_t)(g * 8 + l3) * (HIDDEN * 2) + kk * 128 + swzA, &lds.st.A[g * 1024]);
    }
    *(uint4*)&lds.st.B[wo00] = pack4(b0, b1);
    *(uint4*)&lds.st.B[wo01] = pack4(b2, b3);
    *(uint4*)&lds.st.B[wo10] = pack4(c0, c1);
    *(uint4*)&lds.st.B[wo11] = pack4(c2, c3);
    __syncthreads();
#pragma unroll
    for (int ks = 0; ks < 2; ++ks) {
      short8 a[4], b[4];
#pragma unroll
      for (int mi = 0; mi < 4; mi++) {
        int row = wr * 64 + mi * 16 + (lane & 15);
        int koff = ks * 64 + (l4 << 4);
        a[mi] = *(const short8*)&lds.st.A[row * 128 + (koff ^ ((row & 7) << 4))];
      }
#pragma unroll
      for (int ni = 0; ni < 4; ni++) {
        int row = wc * 64 + ni * 16 + (lane & 15);
        int koff = ks * 64 + (l4 << 4);
        b[ni] = *(const short8*)&lds.st.B[row * 128 + (koff ^ ((row & 7) << 4))];
      }
#pragma unroll
      for (int mi = 0; mi < 4; mi++)
#pragma unroll
        for (int ni = 0; ni < 4; ni++)
          acc[mi][ni] = __builtin_amdgcn_mfma_f32_16x16x32_bf16(a[mi], b[ni], acc[mi][ni], 0, 0, 0);
    }
    __syncthreads();
  }
  // epilogue: h -> LDS (bf16), then act = silu(gate)*up -> global
#pragma unroll
  for (int mi = 0; mi < 4; mi++)
#pragma unroll
    for (int ni = 0; ni < 4; ni++)
#pragma unroll
      for (int r = 0; r < 4; r++) {
        int row = wr * 64 + mi * 16 + ((lane >> 4) << 2) + r;   // C/D: row=(lane>>4)*4+reg
        int col = wc * 64 + ni * 16 + (lane & 15);              //      col=lane&15
        lds.hb[row * 132 + col] = f2bf(acc[mi][ni][r]);
      }
  __syncthreads();
  {
    int r = tid >> 1, ch = (tid & 1) * 32;
    unsigned short* orow = act + (size_t)(rbase + r) * INTER + nt * 64 + ch;
    const unsigned short* hrow = &lds.hb[r * 132];
#pragma unroll
    for (int j = 0; j < 32; j += 4) {
      ushort4 o;
#pragma unroll
      for (int qq = 0; qq < 4; qq++) {
        float g = bf2f(hrow[ch + j + qq]);
        float u = bf2f(hrow[64 + ch + j + qq]);
        float s = g / (1.f + __expf(-g));
        ((unsigned short*)&o)[qq] = f2bf(s * u);
      }
      *(ushort4*)(orow + j) = o;
    }
  }
}

// ============ GEMM2: P[z] = act * w2[e]^T over K-slice z; B reg-staged f32->bf16 ============
__global__ __launch_bounds__(256, 3) void k_gemm2(const float* __restrict__ w2,
    const unsigned short* __restrict__ act, float* __restrict__ P0, float* __restrict__ P1,
    const int* __restrict__ ctrl) {
  struct __align__(16) Lds2 { unsigned char A[16384]; unsigned char B[16384]; };
  __shared__ Lds2 lds;
  int mt = blockIdx.y, ml;
  int e = tile_lookup(ctrl, mt, &ml);
  if (e < 0) return;
  int nt = blockIdx.x;                               // 0..7 : out cols [nt*128, +128)
  int z  = blockIdx.z;                               // K-slice
  int tid = threadIdx.x, lane = tid & 63, wid = tid >> 6, wr = wid >> 1, wc = wid & 1;
  int rbase = ctrl[16 + e] + ml * 128;
  const unsigned char* Ab = (const unsigned char*)(act + (size_t)rbase * INTER);
  int swzA = ((lane & 7) ^ (lane >> 3)) << 4;
  int l3 = lane >> 3, l4 = lane >> 4;
  const int KST = (INTER / 64) / SPLITK;             // 22 k-steps per slice

  int q = tid & 3, rr = tid >> 2, r7 = rr & 7;
  const float* g0 = w2 + (size_t)e * HIDDEN * INTER + (size_t)(nt * 128 + rr) * INTER + q * 16;
  const float* g1 = g0 + (size_t)64 * INTER;
  unsigned wo00 = rr * 128        + (((2 * q)     ^ r7) << 4);
  unsigned wo01 = rr * 128        + (((2 * q + 1) ^ r7) << 4);
  unsigned wo10 = (64 + rr) * 128 + (((2 * q)     ^ r7) << 4);
  unsigned wo11 = (64 + rr) * 128 + (((2 * q + 1) ^ r7) << 4);

  f32x4 acc[4][4];
  f32x4 zero = {0.f, 0.f, 0.f, 0.f};
#pragma unroll
  for (int i = 0; i < 4; i++)
#pragma unroll
    for (int j = 0; j < 4; j++) acc[i][j] = zero;

  for (int s = 0; s < KST; ++s) {
    int kk = z * KST + s;
    const float4* p0 = (const float4*)(g0 + kk * 64);
    const float4* p1 = (const float4*)(g1 + kk * 64);
    float4 b0 = p0[0], b1 = p0[1], b2 = p0[2], b3 = p0[3];
    float4 c0 = p1[0], c1 = p1[1], c2 = p1[2], c3 = p1[3];
#pragma unroll
    for (int i = 0; i < 4; i++) {
      int g = wid * 4 + i;
      gload16(Ab + (size_t)(g * 8 + l3) * (INTER * 2) + kk * 128 + swzA, &lds.A[g * 1024]);
    }
    *(uint4*)&lds.B[wo00] = pack4(b0, b1);
    *(uint4*)&lds.B[wo01] = pack4(b2, b3);
    *(uint4*)&lds.B[wo10] = pack4(c0, c1);
    *(uint4*)&lds.B[wo11] = pack4(c2, c3);
    __syncthreads();
#pragma unroll
    for (int ks = 0; ks < 2; ++ks) {
      short8 a[4], b[4];
#pragma unroll
      for (int mi = 0; mi < 4; mi++) {
        int row = wr * 64 + mi * 16 + (lane & 15);
        int koff = ks * 64 + (l4 << 4);
        a[mi] = *(const short8*)&lds.A[row * 128 + (koff ^ ((row & 7) << 4))];
      }
#pragma unroll
      for (int ni = 0; ni < 4; ni++) {
        int row = wc * 64 + ni * 16 + (lane & 15);
        int koff = ks * 64 + (l4 << 4);
        b[ni] = *(const short8*)&lds.B[row * 128 + (koff ^ ((row & 7) << 4))];
      }
#pragma unroll
      for (int mi = 0; mi < 4; mi++)
#pragma unroll
        for (int ni = 0; ni < 4; ni++)
          acc[mi][ni] = __builtin_amdgcn_mfma_f32_16x16x32_bf16(a[mi], b[ni], acc[mi][ni], 0, 0, 0);
    }
    __syncthreads();
  }
  // plain f32 stores into slice buffer (deterministic; padded rows hold zeros)
  float* P = z ? P1 : P0;
#pragma unroll
  for (int mi = 0; mi < 4; mi++)
#pragma unroll
    for (int ni = 0; ni < 4; ni++) {
      int col = nt * 128 + wc * 64 + ni * 16 + (lane & 15);
#pragma unroll
      for (int r = 0; r < 4; r++) {
        int row = rbase + wr * 64 + mi * 16 + ((lane >> 4) << 2) + r;
        P[(size_t)row * HIDDEN + col] = acc[mi][ni][r];
      }
    }
}

// ---------------- final: out[t] = w0*(P0+P1)[row0] + w1*(P0+P1)[row1] ----------------
__global__ void k_finish(const float* __restrict__ P0, const float* __restrict__ P1,
                         const int* __restrict__ trow, const float* __restrict__ tkw,
                         float* __restrict__ out) {
  int t = blockIdx.x, c = threadIdx.x;
  int r0 = trow[2 * t], r1 = trow[2 * t + 1];
  float w0 = tkw[2 * t], w1 = tkw[2 * t + 1];
  float4 a0 = ((const float4*)(P0 + (size_t)r0 * HIDDEN))[c];
  float4 b0 = ((const float4*)(P1 + (size_t)r0 * HIDDEN))[c];
  float4 a1 = ((const float4*)(P0 + (size_t)r1 * HIDDEN))[c];
  float4 b1 = ((const float4*)(P1 + (size_t)r1 * HIDDEN))[c];
  float4 o;
  o.x = w0 * (a0.x + b0.x) + w1 * (a1.x + b1.x);
  o.y = w0 * (a0.y + b0.y) + w1 * (a1.y + b1.y);
  o.z = w0 * (a0.z + b0.z) + w1 * (a1.z + b1.z);
  o.w = w0 * (a0.w + b0.w) + w1 * (a1.w + b1.w);
  ((float4*)(out + (size_t)t * HIDDEN))[c] = o;
}

extern "C" void kernel_launch(void* const* d_in, const int* in_sizes, int n_in,
                              void* d_out, int out_size, void* d_ws, size_t ws_size,
                              hipStream_t stream) {
  const float* x      = (const float*)d_in[0];
  const float* gating = (const float*)d_in[1];
  const float* w1     = (const float*)d_in[2];
  const float* w2     = (const float*)d_in[3];
  float* out = (float*)d_out;
  char* ws = (char*)d_ws;

  // ws layout (total ~81.4 MB; R2 confirmed ws_size >= 178 MB)
  int*   ctrl = (int*)ws;                                   // cnt[8] cursor[8] base[8]
  int*   tkid = (int*)(ws + 1024);                          // 4096 ints
  float* tkw  = (float*)(ws + 17408);                       // 4096 floats
  int*   rtok = (int*)(ws + 33792);                         // 5120 ints
  int*   trow = (int*)(ws + 54272);                         // 4096 ints
  size_t off_Abf = 131072;
  size_t off_act = off_Abf + (size_t)ROWCAP * HIDDEN * 2;   // +10.49 MB
  size_t off_P0  = off_act + (size_t)ROWCAP * INTER * 2;    // +28.84 MB
  size_t off_P1  = off_P0  + (size_t)ROWCAP * HIDDEN * 4;   // +20.97 MB
  unsigned short* Abf  = (unsigned short*)(ws + off_Abf);
  unsigned short* actb = (unsigned short*)(ws + off_act);
  float* P0 = (float*)(ws + off_P0);
  float* P1 = (float*)(ws + off_P1);

  hipMemsetAsync(ws, 0, 1024, stream);

  k_routing<<<TOKENS / 256, 256, 0, stream>>>(gating, ctrl, tkid, tkw);
  k_base<<<1, 64, 0, stream>>>(ctrl);
  k_fill<<<TOKENS / 256, 256, 0, stream>>>(ctrl, tkid, rtok, trow);
  k_gather<<<ROWCAP, 256, 0, stream>>>(x, ctrl, rtok, Abf);
  k_gemm1<<<dim3(N1 / 128, 40), 256, 0, stream>>>(w1, Abf, actb, ctrl);
  k_gemm2<<<dim3(HIDDEN / 128, 40, SPLITK), 256, 0, stream>>>(w2, actb, P0, P1, ctrl);
  k_finish<<<TOKENS, 256, 0, stream>>>(P0, P1, trow, tkw, out);
}

// Round 5
// 243.644 us; speedup vs baseline: 1.1183x; 1.1183x over previous
//
#include <hip/hip_runtime.h>
#include <hip/hip_bf16.h>

#define TOKENS 2048
#define HIDDEN 1024
#define NEXP   8
#define INTER  2816
#define N1     5632      // 2*INTER
#define ROWCAP 6144      // pad-to-256 worst case: 4096 + 8*255 = 6136
#define MT     24        // ROWCAP/256 m-tiles
#define NT1    44        // gemm1 col tiles (64 inter cols -> 128 B rows each)
#define NT2    8         // gemm2 col tiles (128 out cols)
#define SPLITK 2         // gemm2 K-slices

typedef __attribute__((ext_vector_type(8))) short short8;   // 8 bf16 (MFMA A/B frag)
typedef __attribute__((ext_vector_type(4))) float f32x4;    // MFMA C/D frag

typedef unsigned int __attribute__((address_space(1))) as1_uint;
typedef unsigned int __attribute__((address_space(3))) as3_uint;

__device__ __forceinline__ void gload16(const void* g, void* l) {
  // async global->LDS, 16B/lane, LDS dest = wave-uniform base + lane*16
  __builtin_amdgcn_global_load_lds((const as1_uint*)g, (as3_uint*)l, 16, 0, 0);
}

__device__ __forceinline__ unsigned short f2bf(float f) {  // RNE f32->bf16 (bit trick)
  unsigned u = __float_as_uint(f);
  u += 0x7fff + ((u >> 16) & 1);
  return (unsigned short)(u >> 16);
}
__device__ __forceinline__ float bf2f(unsigned short h) {
  return __uint_as_float(((unsigned)h) << 16);
}
__device__ __forceinline__ unsigned short bfs(float x) {   // compiler fuses pairs -> v_cvt_pk_bf16_f32
  __hip_bfloat16 h = __float2bfloat16(x);
  return *reinterpret_cast<unsigned short*>(&h);
}

// ---------------- routing: softmax->top2->renorm == sigmoid(l0-l1) ----------------
__global__ void k_routing(const float* __restrict__ gate, int* __restrict__ ctrl,
                          int* __restrict__ tkid, float* __restrict__ tkw) {
  int t = blockIdx.x * blockDim.x + threadIdx.x;
  if (t >= TOKENS) return;
  float l[8];
#pragma unroll
  for (int i = 0; i < 8; i++) l[i] = gate[t * 8 + i];
  int i0 = 0; float m0 = l[0];
#pragma unroll
  for (int i = 1; i < 8; i++) if (l[i] > m0) { m0 = l[i]; i0 = i; }
  int i1 = -1; float m1 = -3.4e38f;
#pragma unroll
  for (int i = 0; i < 8; i++) if (i != i0 && l[i] > m1) { m1 = l[i]; i1 = i; }
  float e  = __expf(m1 - m0);
  float w0 = 1.f / (1.f + e);
  float w1 = e / (1.f + e);
  tkid[2 * t] = i0; tkid[2 * t + 1] = i1;
  tkw[2 * t] = w0;  tkw[2 * t + 1] = w1;
  atomicAdd(&ctrl[i0], 1);
  atomicAdd(&ctrl[i1], 1);
}

// ctrl (ints): [0..7]=cnt  [8..15]=cursor  [16..23]=base (256-aligned prefix)
__global__ void k_base(int* ctrl) {
  if (threadIdx.x == 0) {
    int a = 0;
    for (int e = 0; e < 8; e++) { ctrl[16 + e] = a; a += ((ctrl[e] + 255) >> 8) << 8; }
  }
}

__global__ void k_fill(int* __restrict__ ctrl, const int* __restrict__ tkid,
                       int* __restrict__ rtok, int* __restrict__ trow) {
  int t = blockIdx.x * blockDim.x + threadIdx.x;
  if (t >= TOKENS) return;
#pragma unroll
  for (int k = 0; k < 2; k++) {
    int e = tkid[2 * t + k];
    int pos = atomicAdd(&ctrl[8 + e], 1);
    int row = ctrl[16 + e] + pos;
    rtok[row] = t;
    trow[2 * t + k] = row;
  }
}

// gather x rows (f32) -> bf16 A ordered by expert segment; zero padded rows
__global__ void k_gather(const float* __restrict__ x, const int* __restrict__ ctrl,
                         const int* __restrict__ rtok, unsigned short* __restrict__ Abf) {
  int row = blockIdx.x;
  int e = -1, local = 0;
  for (int i = 0; i < 8; i++) {
    int b = ctrl[16 + i], p = ((ctrl[i] + 255) >> 8) << 8;
    if (row >= b && row < b + p) { e = i; local = row - b; break; }
  }
  if (e < 0) return;
  int tid = threadIdx.x;
  unsigned short* dst = Abf + (size_t)row * HIDDEN;
  if (local < ctrl[e]) {
    int t = rtok[row];
    float4 v = ((const float4*)(x + (size_t)t * HIDDEN))[tid];
    ushort4 o; o.x = f2bf(v.x); o.y = f2bf(v.y); o.z = f2bf(v.z); o.w = f2bf(v.w);
    ((ushort4*)dst)[tid] = o;
  } else {
    ushort4 z; z.x = 0; z.y = 0; z.z = 0; z.w = 0;
    ((ushort4*)dst)[tid] = z;
  }
}

__device__ __forceinline__ int tile_lookup(const int* ctrl, int mt, int* ml) {
  int a0 = 0;
  for (int i = 0; i < 8; i++) {
    int pt = (ctrl[i] + 255) >> 8;
    if (mt < a0 + pt) { *ml = mt - a0; return i; }
    a0 += pt;
  }
  return -1;
}

// ============ GEMM1: 256x128 tile, A bf16 gload_lds, B f32 gload_lds -> repack bf16 ========
// Per k-step: [issue A] bar [repack Bf32->Bb swz] bar [issue B[s+1]; MFMA] bar.
// LDS 80KB: A 32K + Bf32 32K + Bb 16K; 512 thr (8 waves, 4m x 2n of 64x64).
__global__ __launch_bounds__(512, 4) void k_gemm1(const float* __restrict__ w1,
    const unsigned short* __restrict__ Abf, unsigned short* __restrict__ act,
    const int* __restrict__ ctrl) {
  union __align__(16) LdsU {
    struct { unsigned char A[32768]; unsigned char Bf[32768]; unsigned char Bb[16384]; } st;
    unsigned short hb[256 * 132];   // 67584 B < 81920
  };
  __shared__ LdsU lds;
  int bid = blockIdx.x;                       // XCD-aware bijective swizzle (1056 % 8 == 0)
  int wg = (bid & 7) * (NT1 * MT / 8) + (bid >> 3);
  int mt = wg / NT1, nt = wg % NT1;
  int ml; int e = tile_lookup(ctrl, mt, &ml);
  if (e < 0) return;
  int tid = threadIdx.x, lane = tid & 63, wid = tid >> 6, wr = wid >> 1, wc = wid & 1;
  int rbase = ctrl[16 + e] + ml * 256;
  const unsigned char* Ab = (const unsigned char*)(Abf + (size_t)rbase * HIDDEN);
  const unsigned char* Bw = (const unsigned char*)(w1 + (size_t)e * N1 * HIDDEN);
  int l3 = lane >> 3, l4 = lane >> 4, l15 = lane & 15;
  int swzA = ((lane & 7) ^ l3) << 4;

  size_t aoff[4], boff[4];
#pragma unroll
  for (int i = 0; i < 4; i++) {
    int g = wid * 4 + i;
    aoff[i] = (size_t)(g * 8 + l3) * (HIDDEN * 2) + swzA;         // A rows g*8+l3
    int r = g * 4 + l4;                                           // B rows g*4+l4 (linear)
    int grow = (r < 64) ? nt * 64 + r : INTER + nt * 64 + (r - 64);
    boff[i] = (size_t)grow * (HIDDEN * 4) + (size_t)l15 * 16;
  }

  f32x4 acc[4][4];
  f32x4 zero = {0.f, 0.f, 0.f, 0.f};
#pragma unroll
  for (int i = 0; i < 4; i++)
#pragma unroll
    for (int j = 0; j < 4; j++) acc[i][j] = zero;

  // prologue: issue B[0] (f32, linear)
#pragma unroll
  for (int i = 0; i < 4; i++)
    gload16(Bw + boff[i], &lds.st.Bf[(wid * 4 + i) * 1024]);

  const int NS = HIDDEN / 64;
  for (int s = 0; s < NS; ++s) {
#pragma unroll
    for (int i = 0; i < 4; i++)
      gload16(Ab + aoff[i] + s * 128, &lds.st.A[(wid * 4 + i) * 1024]);
    __syncthreads();                              // A[s] + B[s] resident
    // repack: contiguous 16B stripes (conflict-free) -> bf16 swizzled, cvt once
#pragma unroll
    for (int i = 0; i < 4; i++) {
      int off = wid * 4096 + i * 1024 + lane * 16;
      f32x4 v = *(const f32x4*)&lds.st.Bf[off];
      int r = off >> 8, jL = (off >> 4) & 15;
      uint2 wv;
      wv.x = (unsigned)bfs(v[0]) | ((unsigned)bfs(v[1]) << 16);
      wv.y = (unsigned)bfs(v[2]) | ((unsigned)bfs(v[3]) << 16);
      *(uint2*)&lds.st.Bb[r * 128 + ((((jL >> 1) ^ (r & 7)) << 4) | ((jL & 1) << 3))] = wv;
    }
    __syncthreads();                              // Bb visible; Bf now dead
    if (s + 1 < NS) {                             // prefetch B[s+1] under MFMA
#pragma unroll
      for (int i = 0; i < 4; i++)
        gload16(Bw + boff[i] + (size_t)(s + 1) * 256, &lds.st.Bf[(wid * 4 + i) * 1024]);
    }
#pragma unroll
    for (int ks = 0; ks < 2; ++ks) {
      short8 a[4], b[4];
#pragma unroll
      for (int mi = 0; mi < 4; mi++) {
        int row = wr * 64 + mi * 16 + l15;
        int koff = ks * 64 + (l4 << 4);
        a[mi] = *(const short8*)&lds.st.A[row * 128 + (koff ^ ((row & 7) << 4))];
      }
#pragma unroll
      for (int ni = 0; ni < 4; ni++) {
        int row = wc * 64 + ni * 16 + l15;
        int koff = ks * 64 + (l4 << 4);
        b[ni] = *(const short8*)&lds.st.Bb[row * 128 + (koff ^ ((row & 7) << 4))];
      }
#pragma unroll
      for (int mi = 0; mi < 4; mi++)
#pragma unroll
        for (int ni = 0; ni < 4; ni++)
          acc[mi][ni] = __builtin_amdgcn_mfma_f32_16x16x32_bf16(a[mi], b[ni], acc[mi][ni], 0, 0, 0);
    }
    __syncthreads();                              // done reading A/Bb before overwrite
  }
  // epilogue: h -> LDS bf16, then act = silu(gate)*up
#pragma unroll
  for (int mi = 0; mi < 4; mi++)
#pragma unroll
    for (int ni = 0; ni < 4; ni++)
#pragma unroll
      for (int r = 0; r < 4; r++) {
        int row = wr * 64 + mi * 16 + (l4 << 2) + r;   // C/D: row=(lane>>4)*4+reg
        int col = wc * 64 + ni * 16 + l15;             //      col=lane&15
        lds.hb[row * 132 + col] = f2bf(acc[mi][ni][r]);
      }
  __syncthreads();
  {
    int r = tid >> 1, ch = (tid & 1) * 32;
    unsigned short* orow = act + (size_t)(rbase + r) * INTER + nt * 64 + ch;
    const unsigned short* hrow = &lds.hb[r * 132];
#pragma unroll
    for (int j = 0; j < 32; j += 4) {
      ushort4 o;
#pragma unroll
      for (int q = 0; q < 4; q++) {
        float g = bf2f(hrow[ch + j + q]);
        float u = bf2f(hrow[64 + ch + j + q]);
        float s = g / (1.f + __expf(-g));
        ((unsigned short*)&o)[q] = f2bf(s * u);
      }
      *(ushort4*)(orow + j) = o;
    }
  }
}

// ============ GEMM2: 256x128 tile, same staging structure, split-K, plain f32 stores ========
__global__ __launch_bounds__(512, 4) void k_gemm2(const float* __restrict__ w2,
    const unsigned short* __restrict__ act, float* __restrict__ Pb,
    const int* __restrict__ ctrl) {
  struct __align__(16) Lds2 { unsigned char A[32768]; unsigned char Bf[32768]; unsigned char Bb[16384]; };
  __shared__ Lds2 lds;
  int bid = blockIdx.x;                       // 384 % 8 == 0
  int wg = (bid & 7) * (NT2 * MT * SPLITK / 8) + (bid >> 3);
  int z = wg / (MT * NT2);
  int rem = wg % (MT * NT2);
  int mt = rem >> 3, nt = rem & 7;
  int ml; int e = tile_lookup(ctrl, mt, &ml);
  if (e < 0) return;
  int tid = threadIdx.x, lane = tid & 63, wid = tid >> 6, wr = wid >> 1, wc = wid & 1;
  int rbase = ctrl[16 + e] + ml * 256;
  const int KST = (INTER / 64) / SPLITK;          // 22
  const unsigned char* Ab = (const unsigned char*)(act + (size_t)rbase * INTER) + (size_t)z * KST * 128;
  const unsigned char* Bw = (const unsigned char*)(w2 + (size_t)e * HIDDEN * INTER) + (size_t)z * KST * 256;
  int l3 = lane >> 3, l4 = lane >> 4, l15 = lane & 15;
  int swzA = ((lane & 7) ^ l3) << 4;

  size_t aoff[4], boff[4];
#pragma unroll
  for (int i = 0; i < 4; i++) {
    int g = wid * 4 + i;
    aoff[i] = (size_t)(g * 8 + l3) * (INTER * 2) + swzA;
    int r = g * 4 + l4;
    boff[i] = (size_t)(nt * 128 + r) * (INTER * 4) + (size_t)l15 * 16;
  }

  f32x4 acc[4][4];
  f32x4 zero = {0.f, 0.f, 0.f, 0.f};
#pragma unroll
  for (int i = 0; i < 4; i++)
#pragma unroll
    for (int j = 0; j < 4; j++) acc[i][j] = zero;

#pragma unroll
  for (int i = 0; i < 4; i++)
    gload16(Bw + boff[i], &lds.Bf[(wid * 4 + i) * 1024]);

  for (int s = 0; s < KST; ++s) {
#pragma unroll
    for (int i = 0; i < 4; i++)
      gload16(Ab + aoff[i] + s * 128, &lds.A[(wid * 4 + i) * 1024]);
    __syncthreads();
#pragma unroll
    for (int i = 0; i < 4; i++) {
      int off = wid * 4096 + i * 1024 + lane * 16;
      f32x4 v = *(const f32x4*)&lds.Bf[off];
      int r = off >> 8, jL = (off >> 4) & 15;
      uint2 wv;
      wv.x = (unsigned)bfs(v[0]) | ((unsigned)bfs(v[1]) << 16);
      wv.y = (unsigned)bfs(v[2]) | ((unsigned)bfs(v[3]) << 16);
      *(uint2*)&lds.Bb[r * 128 + ((((jL >> 1) ^ (r & 7)) << 4) | ((jL & 1) << 3))] = wv;
    }
    __syncthreads();
    if (s + 1 < KST) {
#pragma unroll
      for (int i = 0; i < 4; i++)
        gload16(Bw + boff[i] + (size_t)(s + 1) * 256, &lds.Bf[(wid * 4 + i) * 1024]);
    }
#pragma unroll
    for (int ks = 0; ks < 2; ++ks) {
      short8 a[4], b[4];
#pragma unroll
      for (int mi = 0; mi < 4; mi++) {
        int row = wr * 64 + mi * 16 + l15;
        int koff = ks * 64 + (l4 << 4);
        a[mi] = *(const short8*)&lds.A[row * 128 + (koff ^ ((row & 7) << 4))];
      }
#pragma unroll
      for (int ni = 0; ni < 4; ni++) {
        int row = wc * 64 + ni * 16 + l15;
        int koff = ks * 64 + (l4 << 4);
        b[ni] = *(const short8*)&lds.Bb[row * 128 + (koff ^ ((row & 7) << 4))];
      }
#pragma unroll
      for (int mi = 0; mi < 4; mi++)
#pragma unroll
        for (int ni = 0; ni < 4; ni++)
          acc[mi][ni] = __builtin_amdgcn_mfma_f32_16x16x32_bf16(a[mi], b[ni], acc[mi][ni], 0, 0, 0);
    }
    __syncthreads();
  }
  float* P = Pb + (size_t)z * ROWCAP * HIDDEN;
#pragma unroll
  for (int mi = 0; mi < 4; mi++)
#pragma unroll
    for (int ni = 0; ni < 4; ni++) {
      int col = nt * 128 + wc * 64 + ni * 16 + l15;
#pragma unroll
      for (int r = 0; r < 4; r++) {
        int row = rbase + wr * 64 + mi * 16 + (l4 << 2) + r;
        P[(size_t)row * HIDDEN + col] = acc[mi][ni][r];
      }
    }
}

// ---------------- final: out[t] = w0*(P0+P1)[row0] + w1*(P0+P1)[row1] ----------------
__global__ void k_finish(const float* __restrict__ Pb,
                         const int* __restrict__ trow, const float* __restrict__ tkw,
                         float* __restrict__ out) {
  int t = blockIdx.x, c = threadIdx.x;
  const float* P0 = Pb;
  const float* P1 = Pb + (size_t)ROWCAP * HIDDEN;
  int r0 = trow[2 * t], r1 = trow[2 * t + 1];
  float w0 = tkw[2 * t], w1 = tkw[2 * t + 1];
  float4 a0 = ((const float4*)(P0 + (size_t)r0 * HIDDEN))[c];
  float4 b0 = ((const float4*)(P1 + (size_t)r0 * HIDDEN))[c];
  float4 a1 = ((const float4*)(P0 + (size_t)r1 * HIDDEN))[c];
  float4 b1 = ((const float4*)(P1 + (size_t)r1 * HIDDEN))[c];
  float4 o;
  o.x = w0 * (a0.x + b0.x) + w1 * (a1.x + b1.x);
  o.y = w0 * (a0.y + b0.y) + w1 * (a1.y + b1.y);
  o.z = w0 * (a0.z + b0.z) + w1 * (a1.z + b1.z);
  o.w = w0 * (a0.w + b0.w) + w1 * (a1.w + b1.w);
  ((float4*)(out + (size_t)t * HIDDEN))[c] = o;
}

extern "C" void kernel_launch(void* const* d_in, const int* in_sizes, int n_in,
                              void* d_out, int out_size, void* d_ws, size_t ws_size,
                              hipStream_t stream) {
  const float* x      = (const float*)d_in[0];
  const float* gating = (const float*)d_in[1];
  const float* w1     = (const float*)d_in[2];
  const float* w2     = (const float*)d_in[3];
  float* out = (float*)d_out;
  char* ws = (char*)d_ws;

  // ws layout (~148 MB; ws_size >= 178 MB confirmed in R2)
  int*   ctrl = (int*)ws;                                   // cnt[8] cursor[8] base[8]
  int*   tkid = (int*)(ws + 4096);                          // 4096 ints
  float* tkw  = (float*)(ws + 24576);                       // 4096 floats
  int*   rtok = (int*)(ws + 45056);                         // 6144 ints
  int*   trow = (int*)(ws + 73728);                         // 4096 ints
  size_t off_Abf = 131072;
  size_t off_act = off_Abf + (size_t)ROWCAP * HIDDEN * 2;   // +12.58 MB
  size_t off_P   = off_act + (size_t)ROWCAP * INTER * 2;    // +34.60 MB
  unsigned short* Abf  = (unsigned short*)(ws + off_Abf);
  unsigned short* actb = (unsigned short*)(ws + off_act);
  float* Pb = (float*)(ws + off_P);                         // SPLITK x ROWCAP x HIDDEN f32

  hipMemsetAsync(ws, 0, 1024, stream);

  k_routing<<<TOKENS / 256, 256, 0, stream>>>(gating, ctrl, tkid, tkw);
  k_base<<<1, 64, 0, stream>>>(ctrl);
  k_fill<<<TOKENS / 256, 256, 0, stream>>>(ctrl, tkid, rtok, trow);
  k_gather<<<ROWCAP, 256, 0, stream>>>(x, ctrl, rtok, Abf);
  k_gemm1<<<NT1 * MT, 512, 0, stream>>>(w1, Abf, actb, ctrl);
  k_gemm2<<<NT2 * MT * SPLITK, 512, 0, stream>>>(w2, actb, Pb, ctrl);
  k_finish<<<TOKENS, 256, 0, stream>>>(Pb, trow, tkw, out);
}

// Round 6
// 239.186 us; speedup vs baseline: 1.1391x; 1.0186x over previous
//
#include <hip/hip_runtime.h>
#include <hip/hip_bf16.h>

#define TOKENS 2048
#define HIDDEN 1024
#define NEXP   8
#define INTER  2816
#define N1     5632      // 2*INTER
#define ROWCAP 5120      // 4096 + 8*127 = 5112 worst case, 128-pad
#define MT     40        // ROWCAP/128 m-tiles
#define NT1    44        // gemm1 col tiles (64 gate + 64 up cols)
#define NT2    8         // gemm2 col tiles (128 out cols)
#define SPLITK 2         // gemm2 K-slices

typedef __attribute__((ext_vector_type(8))) short short8;   // 8 bf16 (MFMA A/B frag)
typedef __attribute__((ext_vector_type(4))) float f32x4;    // MFMA C/D frag

typedef unsigned int __attribute__((address_space(1))) as1_uint;
typedef unsigned int __attribute__((address_space(3))) as3_uint;

__device__ __forceinline__ void gload16(const void* g, void* l) {
  // async global->LDS, 16B/lane, LDS dest = wave-uniform base + lane*16
  __builtin_amdgcn_global_load_lds((const as1_uint*)g, (as3_uint*)l, 16, 0, 0);
}

__device__ __forceinline__ unsigned short f2bf(float f) {  // RNE f32->bf16 (bit trick)
  unsigned u = __float_as_uint(f);
  u += 0x7fff + ((u >> 16) & 1);
  return (unsigned short)(u >> 16);
}
__device__ __forceinline__ float bf2f(unsigned short h) {
  return __uint_as_float(((unsigned)h) << 16);
}
__device__ __forceinline__ unsigned short bfs(float x) {   // compiler fuses pairs -> v_cvt_pk_bf16_f32
  __hip_bfloat16 h = __float2bfloat16(x);
  return *reinterpret_cast<unsigned short*>(&h);
}
__device__ __forceinline__ short8 pack8(f32x4 lo, f32x4 hi) {  // 8 f32 -> bf16 frag
  short8 o;
  o[0] = (short)bfs(lo[0]); o[1] = (short)bfs(lo[1]); o[2] = (short)bfs(lo[2]); o[3] = (short)bfs(lo[3]);
  o[4] = (short)bfs(hi[0]); o[5] = (short)bfs(hi[1]); o[6] = (short)bfs(hi[2]); o[7] = (short)bfs(hi[3]);
  return o;
}

// ---------------- routing: softmax->top2->renorm == sigmoid(l0-l1) ----------------
__global__ void k_routing(const float* __restrict__ gate, int* __restrict__ ctrl,
                          int* __restrict__ tkid, float* __restrict__ tkw) {
  int t = blockIdx.x * blockDim.x + threadIdx.x;
  if (t >= TOKENS) return;
  float l[8];
#pragma unroll
  for (int i = 0; i < 8; i++) l[i] = gate[t * 8 + i];
  int i0 = 0; float m0 = l[0];
#pragma unroll
  for (int i = 1; i < 8; i++) if (l[i] > m0) { m0 = l[i]; i0 = i; }
  int i1 = -1; float m1 = -3.4e38f;
#pragma unroll
  for (int i = 0; i < 8; i++) if (i != i0 && l[i] > m1) { m1 = l[i]; i1 = i; }
  float e  = __expf(m1 - m0);
  float w0 = 1.f / (1.f + e);
  float w1 = e / (1.f + e);
  tkid[2 * t] = i0; tkid[2 * t + 1] = i1;
  tkw[2 * t] = w0;  tkw[2 * t + 1] = w1;
  atomicAdd(&ctrl[i0], 1);
  atomicAdd(&ctrl[i1], 1);
}

// ctrl (ints): [0..7]=cnt  [8..15]=cursor  [16..23]=base (128-aligned prefix)
__global__ void k_base(int* ctrl) {
  if (threadIdx.x == 0) {
    int a = 0;
    for (int e = 0; e < 8; e++) { ctrl[16 + e] = a; a += ((ctrl[e] + 127) >> 7) << 7; }
  }
}

__global__ void k_fill(int* __restrict__ ctrl, const int* __restrict__ tkid,
                       int* __restrict__ rtok, int* __restrict__ trow) {
  int t = blockIdx.x * blockDim.x + threadIdx.x;
  if (t >= TOKENS) return;
#pragma unroll
  for (int k = 0; k < 2; k++) {
    int e = tkid[2 * t + k];
    int pos = atomicAdd(&ctrl[8 + e], 1);
    int row = ctrl[16 + e] + pos;
    rtok[row] = t;
    trow[2 * t + k] = row;
  }
}

// gather x rows (f32) -> bf16 A ordered by expert segment; zero padded rows
__global__ void k_gather(const float* __restrict__ x, const int* __restrict__ ctrl,
                         const int* __restrict__ rtok, unsigned short* __restrict__ Abf) {
  int row = blockIdx.x;
  int e = -1, local = 0;
  for (int i = 0; i < 8; i++) {
    int b = ctrl[16 + i], p = ((ctrl[i] + 127) >> 7) << 7;
    if (row >= b && row < b + p) { e = i; local = row - b; break; }
  }
  if (e < 0) return;
  int tid = threadIdx.x;
  unsigned short* dst = Abf + (size_t)row * HIDDEN;
  if (local < ctrl[e]) {
    int t = rtok[row];
    float4 v = ((const float4*)(x + (size_t)t * HIDDEN))[tid];
    ushort4 o; o.x = f2bf(v.x); o.y = f2bf(v.y); o.z = f2bf(v.z); o.w = f2bf(v.w);
    ((ushort4*)dst)[tid] = o;
  } else {
    ushort4 z; z.x = 0; z.y = 0; z.z = 0; z.w = 0;
    ((ushort4*)dst)[tid] = z;
  }
}

__device__ __forceinline__ int tile_lookup(const int* ctrl, int mt, int* ml) {
  int a0 = 0;
  for (int i = 0; i < 8; i++) {
    int pt = (ctrl[i] + 127) >> 7;
    if (mt < a0 + pt) { *ml = mt - a0; return i; }
    a0 += pt;
  }
  return -1;
}

// ============ GEMM1: 128x128 tile, A bf16 gload_lds, B f32 gload_lds + cvt-on-read ========
// A [128][64] bf16 (16K, 8-deep XOR swz); B [128][64] f32 (32K, 16-deep XOR swz:
// f32 rows are 256B = 0 mod 32 banks, so conflict-freedom needs the full r&15 XOR).
// 2 barriers/k-step (m97 structure), 48KB LDS -> 3 blocks/CU.
__global__ __launch_bounds__(256, 3) void k_gemm1(const float* __restrict__ w1,
    const unsigned short* __restrict__ Abf, unsigned short* __restrict__ act,
    const int* __restrict__ ctrl) {
  union __align__(16) LdsU {
    struct { unsigned char A[16384]; unsigned char Bf[32768]; } st;
    unsigned short hb[128 * 132];   // 33792 B
  };
  __shared__ LdsU lds;
  int bid = blockIdx.x;                        // 1760 % 8 == 0, bijective XCD swizzle
  int wg = (bid & 7) * (NT1 * MT / 8) + (bid >> 3);
  int nt = wg / MT, mt = wg % MT;              // nt-major: XCD chunk shares B panel
  int ml; int e = tile_lookup(ctrl, mt, &ml);
  if (e < 0) return;
  int tid = threadIdx.x, lane = tid & 63, wid = tid >> 6, wr = wid >> 1, wc = wid & 1;
  int rbase = ctrl[16 + e] + ml * 128;
  const unsigned char* Ab = (const unsigned char*)(Abf + (size_t)rbase * HIDDEN);
  const unsigned char* Bw = (const unsigned char*)(w1 + (size_t)e * N1 * HIDDEN);
  int l3 = lane >> 3, l4 = lane >> 4, l15 = lane & 15;
  int swzA = ((lane & 7) ^ l3) << 4;

  unsigned aoff[4], boff[8];
#pragma unroll
  for (int i = 0; i < 4; i++) {
    int g = wid * 4 + i;                       // 16 groups of 8 A-rows
    aoff[i] = (unsigned)(g * 8 + l3) * (HIDDEN * 2) + swzA;
  }
#pragma unroll
  for (int i = 0; i < 8; i++) {
    int r = (wid * 8 + i) * 4 + l4;            // 32 groups of 4 f32 B-rows
    int grow = (r < 64) ? nt * 64 + r : INTER + nt * 64 + (r - 64);
    boff[i] = (unsigned)grow * (HIDDEN * 4) + ((l15 ^ (r & 15)) << 4);  // pre-swizzled src
  }

  f32x4 acc[4][4];
  f32x4 zero = {0.f, 0.f, 0.f, 0.f};
#pragma unroll
  for (int i = 0; i < 4; i++)
#pragma unroll
    for (int j = 0; j < 4; j++) acc[i][j] = zero;

  for (int kk = 0; kk < HIDDEN / 64; ++kk) {
#pragma unroll
    for (int i = 0; i < 4; i++)
      gload16(Ab + (size_t)aoff[i] + kk * 128, &lds.st.A[(wid * 4 + i) * 1024]);
#pragma unroll
    for (int i = 0; i < 8; i++)
      gload16(Bw + (size_t)boff[i] + kk * 256, &lds.st.Bf[(wid * 8 + i) * 1024]);
    __syncthreads();
#pragma unroll
    for (int ks = 0; ks < 2; ++ks) {
      short8 a[4], b[4];
#pragma unroll
      for (int mi = 0; mi < 4; mi++) {
        int row = wr * 64 + mi * 16 + l15;
        int koff = ks * 64 + (l4 << 4);
        a[mi] = *(const short8*)&lds.st.A[row * 128 + (koff ^ ((row & 7) << 4))];
      }
#pragma unroll
      for (int ni = 0; ni < 4; ni++) {
        int r = wc * 64 + ni * 16 + l15;
        int c = ks * 8 + l4 * 2;               // 16B chunk of k-bytes within 256B row
        f32x4 lo = *(const f32x4*)&lds.st.Bf[r * 256 + ((c ^ (r & 15)) << 4)];
        f32x4 hi = *(const f32x4*)&lds.st.Bf[r * 256 + (((c + 1) ^ (r & 15)) << 4)];
        b[ni] = pack8(lo, hi);
      }
#pragma unroll
      for (int mi = 0; mi < 4; mi++)
#pragma unroll
        for (int ni = 0; ni < 4; ni++)
          acc[mi][ni] = __builtin_amdgcn_mfma_f32_16x16x32_bf16(a[mi], b[ni], acc[mi][ni], 0, 0, 0);
    }
    __syncthreads();
  }
  // epilogue: h -> LDS bf16, then act = silu(gate)*up -> global
#pragma unroll
  for (int mi = 0; mi < 4; mi++)
#pragma unroll
    for (int ni = 0; ni < 4; ni++)
#pragma unroll
      for (int r = 0; r < 4; r++) {
        int row = wr * 64 + mi * 16 + (l4 << 2) + r;   // C/D: row=(lane>>4)*4+reg
        int col = wc * 64 + ni * 16 + l15;             //      col=lane&15
        lds.hb[row * 132 + col] = f2bf(acc[mi][ni][r]);
      }
  __syncthreads();
  {
    int r = tid >> 1, ch = (tid & 1) * 32;
    unsigned short* orow = act + (size_t)(rbase + r) * INTER + nt * 64 + ch;
    const unsigned short* hrow = &lds.hb[r * 132];
#pragma unroll
    for (int j = 0; j < 32; j += 4) {
      ushort4 o;
#pragma unroll
      for (int q = 0; q < 4; q++) {
        float g = bf2f(hrow[ch + j + q]);
        float u = bf2f(hrow[64 + ch + j + q]);
        float s = g / (1.f + __expf(-g));
        ((unsigned short*)&o)[q] = f2bf(s * u);
      }
      *(ushort4*)(orow + j) = o;
    }
  }
}

// ============ GEMM2: 128x128 tile, same staging, split-K, plain f32 stores ============
__global__ __launch_bounds__(256, 3) void k_gemm2(const float* __restrict__ w2,
    const unsigned short* __restrict__ act, float* __restrict__ Pb,
    const int* __restrict__ ctrl) {
  struct __align__(16) Lds2 { unsigned char A[16384]; unsigned char Bf[32768]; };
  __shared__ Lds2 lds;
  int bid = blockIdx.x;                        // 640 % 8 == 0
  int wg = (bid & 7) * (NT2 * MT * SPLITK / 8) + (bid >> 3);
  int mt = wg % MT;
  int p = wg / MT;                             // 0..15
  int z = p & 1, nt = p >> 1;                  // consecutive wg share (nt,z) panel
  int ml; int e = tile_lookup(ctrl, mt, &ml);
  if (e < 0) return;
  int tid = threadIdx.x, lane = tid & 63, wid = tid >> 6, wr = wid >> 1, wc = wid & 1;
  int rbase = ctrl[16 + e] + ml * 128;
  const int KST = (INTER / 64) / SPLITK;       // 22 k-steps per slice
  const unsigned char* Ab = (const unsigned char*)(act + (size_t)rbase * INTER) + (size_t)z * KST * 128;
  const unsigned char* Bw = (const unsigned char*)(w2 + (size_t)e * HIDDEN * INTER) + (size_t)z * KST * 256;
  int l3 = lane >> 3, l4 = lane >> 4, l15 = lane & 15;
  int swzA = ((lane & 7) ^ l3) << 4;

  unsigned aoff[4], boff[8];
#pragma unroll
  for (int i = 0; i < 4; i++) {
    int g = wid * 4 + i;
    aoff[i] = (unsigned)(g * 8 + l3) * (INTER * 2) + swzA;
  }
#pragma unroll
  for (int i = 0; i < 8; i++) {
    int r = (wid * 8 + i) * 4 + l4;
    boff[i] = (unsigned)(nt * 128 + r) * (INTER * 4) + ((l15 ^ (r & 15)) << 4);
  }

  f32x4 acc[4][4];
  f32x4 zero = {0.f, 0.f, 0.f, 0.f};
#pragma unroll
  for (int i = 0; i < 4; i++)
#pragma unroll
    for (int j = 0; j < 4; j++) acc[i][j] = zero;

  for (int s = 0; s < KST; ++s) {
#pragma unroll
    for (int i = 0; i < 4; i++)
      gload16(Ab + (size_t)aoff[i] + s * 128, &lds.A[(wid * 4 + i) * 1024]);
#pragma unroll
    for (int i = 0; i < 8; i++)
      gload16(Bw + (size_t)boff[i] + s * 256, &lds.Bf[(wid * 8 + i) * 1024]);
    __syncthreads();
#pragma unroll
    for (int ks = 0; ks < 2; ++ks) {
      short8 a[4], b[4];
#pragma unroll
      for (int mi = 0; mi < 4; mi++) {
        int row = wr * 64 + mi * 16 + l15;
        int koff = ks * 64 + (l4 << 4);
        a[mi] = *(const short8*)&lds.A[row * 128 + (koff ^ ((row & 7) << 4))];
      }
#pragma unroll
      for (int ni = 0; ni < 4; ni++) {
        int r = wc * 64 + ni * 16 + l15;
        int c = ks * 8 + l4 * 2;
        f32x4 lo = *(const f32x4*)&lds.Bf[r * 256 + ((c ^ (r & 15)) << 4)];
        f32x4 hi = *(const f32x4*)&lds.Bf[r * 256 + (((c + 1) ^ (r & 15)) << 4)];
        b[ni] = pack8(lo, hi);
      }
#pragma unroll
      for (int mi = 0; mi < 4; mi++)
#pragma unroll
        for (int ni = 0; ni < 4; ni++)
          acc[mi][ni] = __builtin_amdgcn_mfma_f32_16x16x32_bf16(a[mi], b[ni], acc[mi][ni], 0, 0, 0);
    }
    __syncthreads();
  }
  float* P = Pb + (size_t)z * ROWCAP * HIDDEN;
#pragma unroll
  for (int mi = 0; mi < 4; mi++)
#pragma unroll
    for (int ni = 0; ni < 4; ni++) {
      int col = nt * 128 + wc * 64 + ni * 16 + l15;
#pragma unroll
      for (int r = 0; r < 4; r++) {
        int row = rbase + wr * 64 + mi * 16 + (l4 << 2) + r;
        P[(size_t)row * HIDDEN + col] = acc[mi][ni][r];
      }
    }
}

// ---------------- final: out[t] = w0*(P0+P1)[row0] + w1*(P0+P1)[row1] ----------------
__global__ void k_finish(const float* __restrict__ Pb,
                         const int* __restrict__ trow, const float* __restrict__ tkw,
                         float* __restrict__ out) {
  int t = blockIdx.x, c = threadIdx.x;
  const float* P0 = Pb;
  const float* P1 = Pb + (size_t)ROWCAP * HIDDEN;
  int r0 = trow[2 * t], r1 = trow[2 * t + 1];
  float w0 = tkw[2 * t], w1 = tkw[2 * t + 1];
  float4 a0 = ((const float4*)(P0 + (size_t)r0 * HIDDEN))[c];
  float4 b0 = ((const float4*)(P1 + (size_t)r0 * HIDDEN))[c];
  float4 a1 = ((const float4*)(P0 + (size_t)r1 * HIDDEN))[c];
  float4 b1 = ((const float4*)(P1 + (size_t)r1 * HIDDEN))[c];
  float4 o;
  o.x = w0 * (a0.x + b0.x) + w1 * (a1.x + b1.x);
  o.y = w0 * (a0.y + b0.y) + w1 * (a1.y + b1.y);
  o.z = w0 * (a0.z + b0.z) + w1 * (a1.z + b1.z);
  o.w = w0 * (a0.w + b0.w) + w1 * (a1.w + b1.w);
  ((float4*)(out + (size_t)t * HIDDEN))[c] = o;
}

extern "C" void kernel_launch(void* const* d_in, const int* in_sizes, int n_in,
                              void* d_out, int out_size, void* d_ws, size_t ws_size,
                              hipStream_t stream) {
  const float* x      = (const float*)d_in[0];
  const float* gating = (const float*)d_in[1];
  const float* w1     = (const float*)d_in[2];
  const float* w2     = (const float*)d_in[3];
  float* out = (float*)d_out;
  char* ws = (char*)d_ws;

  // ws layout (~81 MB; ws_size >= 178 MB confirmed)
  int*   ctrl = (int*)ws;                                   // cnt[8] cursor[8] base[8]
  int*   tkid = (int*)(ws + 4096);
  float* tkw  = (float*)(ws + 24576);
  int*   rtok = (int*)(ws + 45056);
  int*   trow = (int*)(ws + 73728);
  size_t off_Abf = 131072;
  size_t off_act = off_Abf + (size_t)ROWCAP * HIDDEN * 2;   // +10.49 MB
  size_t off_P   = off_act + (size_t)ROWCAP * INTER * 2;    // +28.84 MB
  unsigned short* Abf  = (unsigned short*)(ws + off_Abf);
  unsigned short* actb = (unsigned short*)(ws + off_act);
  float* Pb = (float*)(ws + off_P);                         // SPLITK x ROWCAP x HIDDEN f32

  hipMemsetAsync(ws, 0, 1024, stream);

  k_routing<<<TOKENS / 256, 256, 0, stream>>>(gating, ctrl, tkid, tkw);
  k_base<<<1, 64, 0, stream>>>(ctrl);
  k_fill<<<TOKENS / 256, 256, 0, stream>>>(ctrl, tkid, rtok, trow);
  k_gather<<<ROWCAP, 256, 0, stream>>>(x, ctrl, rtok, Abf);
  k_gemm1<<<NT1 * MT, 256, 0, stream>>>(w1, Abf, actb, ctrl);
  k_gemm2<<<NT2 * MT * SPLITK, 256, 0, stream>>>(w2, actb, Pb, ctrl);
  k_finish<<<TOKENS, 256, 0, stream>>>(Pb, trow, tkw, out);
}